// Round 19
// baseline (265.357 us; speedup 1.0000x reference)
//
#include <hip/hip_runtime.h>

#define B_  4
#define S_  4096
#define DH  1024
#define DL  256
#define KK  64
#define KH  4
#define WW  9

typedef unsigned short ushort_t;
typedef _Float16 f16;
typedef _Float16 f16x8 __attribute__((ext_vector_type(8)));
typedef float  f32x4  __attribute__((ext_vector_type(4)));

__device__ __forceinline__ void gld_lds16(const void* g, void* lds_uniform_base) {
    __builtin_amdgcn_global_load_lds(
        (const __attribute__((address_space(1))) unsigned int*)g,
        (__attribute__((address_space(3))) unsigned int*)lds_uniform_base,
        16, 0, 0);
}

// ---------------------------------------------------------------------------
// A-DIRECT 2-limb fp16 MFMA GEMM, 64x64 tile, BK=64, 256 threads / 4 waves.
// A fragments are loaded GLOBAL -> REGISTERS (no LDS): A-panels have little
// reuse (N small), and register loads are tracked by the issuing wave's own
// vmcnt — they ride across barriers (r18 showed LDS-staged prefetch cannot:
// the barrier drain waits on it).  Only B (tiny, L2-hot) goes through LDS,
// double-buffered, with COUNTED vmcnt (T4): per k-step issue
//   { B-stage(t+1): 4 gld_lds ; [gidx: 2] ; A(t+1): 8 reg-loads }  then
//   compute(t) ; s_waitcnt vmcnt(8)  (waits oldest 4-6 = B+gidx only; A's 8
//   stay in flight) ; raw s_barrier ; sched_barrier(0).
//   acc0 += ah*bh ;  acc1 += ah*bl + al*bh ;  x = acc0 + acc1/2048 + bias
// AFP32: A raw fp32, limb-split in-register at use (bit-identical).
// GATHER: per-lane gathered A rows (plain per-lane global loads).
// OUTMODE 1: fp32 C + f16 h/l limbs.  OUTMODE 2: f16 Ch only.
// ---------------------------------------------------------------------------
template<bool AFP32, bool GATHER, int OUTMODE, int KT>
__global__ __launch_bounds__(256)
void gemm_adirect(const float* __restrict__ Af,
                  const ushort_t* __restrict__ Ah, const ushort_t* __restrict__ Al,
                  const ushort_t* __restrict__ Bh, const ushort_t* __restrict__ Bl,
                  const float* __restrict__ bias, float* __restrict__ C,
                  ushort_t* __restrict__ Ch, ushort_t* __restrict__ Cl,
                  const int* __restrict__ gidx, int N, int nbx)
{
    constexpr int NT = KT / 64;
    __shared__ __align__(16) ushort_t Bbuf[2][2][64 * 64];   // 32 KB total

    const int tid = threadIdx.x;
    const int w = tid >> 6, l = tid & 63;
    const int wm = w >> 1, wn = w & 1;          // 2m x 2n wave grid
    const int lr = l & 15, lk = l >> 4;
    const int cpx = gridDim.x >> 3;
    const int orig = (blockIdx.x & 7) * cpx + (blockIdx.x >> 3);
    const int m0 = (orig / nbx) * 64, n0 = (orig % nbx) * 64;
    const int ar0 = m0 + wm * 32 + lr;          // this lane's mf=0 A row

    f32x4 af0[2][2][2], af1[2][2][2];           // AFP32 reg tiles (mf,ks,half)
    f16x8 ahr0[2][2], alr0[2][2], ahr1[2][2], alr1[2][2];   // f16 reg tiles

    auto stageB = [&](int buf, int k0) {
        #pragma unroll
        for (int it = 0; it < 2; ++it) {
            const int c = it * 256 + tid;
            const int r = c >> 3, kp = c & 7;
            const int kl = kp ^ (r & 7);
            const size_t off = (size_t)(n0 + r) * KT + k0 + kl * 8;
            gld_lds16(Bh + off, &Bbuf[buf][0][(size_t)c * 8]);
            gld_lds16(Bl + off, &Bbuf[buf][1][(size_t)c * 8]);
        }
    };
    auto loadAf = [&](f32x4 ar[2][2][2], int k0) {
        #pragma unroll
        for (int mf = 0; mf < 2; ++mf)
            #pragma unroll
            for (int ks = 0; ks < 2; ++ks) {
                const float* p = Af + (size_t)(ar0 + mf * 16) * KT + k0 + ks * 32 + lk * 8;
                ar[mf][ks][0] = *(const f32x4*)p;
                ar[mf][ks][1] = *(const f32x4*)(p + 4);
            }
    };
    auto loadAg = [&](f16x8 ha[2][2], f16x8 la[2][2], int k0) {
        const int head = k0 >> 8, kk = k0 & (DL - 1);
        #pragma unroll
        for (int mf = 0; mf < 2; ++mf) {
            const int row = gidx[(ar0 + mf * 16) * KH + head];
            #pragma unroll
            for (int ks = 0; ks < 2; ++ks) {
                const size_t off = (size_t)row * DL + kk + ks * 32 + lk * 8;
                ha[mf][ks] = *(const f16x8*)(Ah + off);
                la[mf][ks] = *(const f16x8*)(Al + off);
            }
        }
    };

    f32x4 acc0[2][2] = {};
    f32x4 acc1[2][2] = {};

    auto computeT = [&](f32x4 arf[2][2][2], f16x8 arh[2][2], f16x8 arl[2][2], int buf) {
        #pragma unroll
        for (int ks = 0; ks < 2; ++ks) {
            f16x8 ah[2], al[2];
            #pragma unroll
            for (int mf = 0; mf < 2; ++mf) {
                if (AFP32) {
                    #pragma unroll
                    for (int e = 0; e < 8; ++e) {
                        const float xv = (e < 4) ? arf[mf][ks][0][e] : arf[mf][ks][1][e - 4];
                        const f16 h = (f16)xv;
                        ah[mf][e] = h;
                        al[mf][e] = (f16)((xv - (float)h) * 2048.0f);
                    }
                } else {
                    ah[mf] = arh[mf][ks];
                    al[mf] = arl[mf][ks];
                }
            }
            #pragma unroll
            for (int nf = 0; nf < 2; ++nf) {
                const int row = wn * 32 + nf * 16 + lr;
                const int kb  = ks * 4 + lk;
                const int o   = row * 64 + ((kb ^ (row & 7)) << 3);
                const f16x8 bh = *(const f16x8*)&Bbuf[buf][0][o];
                const f16x8 bl = *(const f16x8*)&Bbuf[buf][1][o];
                #pragma unroll
                for (int mf = 0; mf < 2; ++mf) {
                    acc0[mf][nf] = __builtin_amdgcn_mfma_f32_16x16x32_f16(
                        ah[mf], bh, acc0[mf][nf], 0, 0, 0);
                    acc1[mf][nf] = __builtin_amdgcn_mfma_f32_16x16x32_f16(
                        ah[mf], bl, acc1[mf][nf], 0, 0, 0);
                    acc1[mf][nf] = __builtin_amdgcn_mfma_f32_16x16x32_f16(
                        al[mf], bh, acc1[mf][nf], 0, 0, 0);
                }
            }
        }
    };

    // prologue: tile 0 into buf0 / reg-set 0
    stageB(0, 0);
    if (AFP32) loadAf(af0, 0); else loadAg(ahr0, alr0, 0);
    asm volatile("s_waitcnt vmcnt(0)" ::: "memory");
    __builtin_amdgcn_s_barrier();
    __builtin_amdgcn_sched_barrier(0);

    #pragma unroll 1
    for (int t = 0; t < NT; t += 2) {
        // half 1: prefetch t+1 -> buf1/set1 ; compute t from buf0/set0
        if (t + 1 < NT) {
            stageB(1, (t + 1) * 64);
            if (AFP32) loadAf(af1, (t + 1) * 64); else loadAg(ahr1, alr1, (t + 1) * 64);
        }
        computeT(af0, ahr0, alr0, 0);
        if (t + 1 < NT) { asm volatile("s_waitcnt vmcnt(8)" ::: "memory"); }
        else            { asm volatile("s_waitcnt vmcnt(0)" ::: "memory"); }
        __builtin_amdgcn_s_barrier();
        __builtin_amdgcn_sched_barrier(0);
        if (t + 1 < NT) {
            // half 2: prefetch t+2 -> buf0/set0 ; compute t+1 from buf1/set1
            if (t + 2 < NT) {
                stageB(0, (t + 2) * 64);
                if (AFP32) loadAf(af0, (t + 2) * 64); else loadAg(ahr0, alr0, (t + 2) * 64);
            }
            computeT(af1, ahr1, alr1, 1);
            if (t + 2 < NT) { asm volatile("s_waitcnt vmcnt(8)" ::: "memory"); }
            else            { asm volatile("s_waitcnt vmcnt(0)" ::: "memory"); }
            __builtin_amdgcn_s_barrier();
            __builtin_amdgcn_sched_barrier(0);
        }
    }

    float bv[2];
    #pragma unroll
    for (int nf = 0; nf < 2; ++nf)
        bv[nf] = bias[n0 + wn * 32 + nf * 16 + lr];
    #pragma unroll
    for (int mf = 0; mf < 2; ++mf)
        #pragma unroll
        for (int nf = 0; nf < 2; ++nf)
            #pragma unroll
            for (int r = 0; r < 4; ++r) {
                const int m = m0 + wm * 32 + mf * 16 + lk * 4 + r;
                const int n = n0 + wn * 32 + nf * 16 + lr;
                float x = acc0[mf][nf][r] + acc1[mf][nf][r] * (1.0f / 2048.0f) + bv[nf];
                x = fmaxf(x, 0.f);
                const f16 h = (f16)x;
                if (OUTMODE == 2) {
                    Ch[(size_t)m * N + n] = __builtin_bit_cast(ushort_t, h);
                } else {
                    C[(size_t)m * N + n] = x;
                    Ch[(size_t)m * N + n] = __builtin_bit_cast(ushort_t, h);
                    const f16 lo = (f16)((x - (float)h) * 2048.0f);
                    Cl[(size_t)m * N + n] = __builtin_bit_cast(ushort_t, lo);
                }
            }
}

// ---------------------------------------------------------------------------
// 1-limb fp16 GEMM for v = relu(q2 @ Wu + bu): 128x128 tile, 512 threads,
// single-buffer 2-barrier (r17-measured form).
// ---------------------------------------------------------------------------
__global__ __launch_bounds__(512)
void mfma_gemm1l(const ushort_t* __restrict__ Ah, const ushort_t* __restrict__ Bh,
                 const float* __restrict__ bias, ushort_t* __restrict__ Ch,
                 int K, int N, int nbx)
{
    __shared__ __align__(16) ushort_t Ash[128 * 64];   // 16KB
    __shared__ __align__(16) ushort_t Bsh[128 * 64];   // 16KB

    const int tid = threadIdx.x;
    const int w = tid >> 6, l = tid & 63;
    const int wm = w >> 1, wn = w & 1;          // 4m x 2n wave grid
    const int lr = l & 15, lk = l >> 4;
    const int cpx = gridDim.x >> 3;
    const int orig = (blockIdx.x & 7) * cpx + (blockIdx.x >> 3);
    const int m0 = (orig / nbx) * 128, n0 = (orig % nbx) * 128;

    f32x4 acc0[2][4] = {};

    for (int k0 = 0; k0 < K; k0 += 64) {
        #pragma unroll
        for (int it = 0; it < 2; ++it) {
            const int c = it * 512 + tid;       // 0..1023
            const int r = c >> 3, kp = c & 7;
            const int kl = kp ^ (r & 7);
            const size_t offA = (size_t)(m0 + r) * K + k0 + kl * 8;
            const size_t offB = (size_t)(n0 + r) * K + k0 + kl * 8;
            gld_lds16(Ah + offA, &Ash[(size_t)c * 8]);
            gld_lds16(Bh + offB, &Bsh[(size_t)c * 8]);
        }
        __syncthreads();

        #pragma unroll
        for (int ks = 0; ks < 2; ++ks) {
            f16x8 ah[2];
            #pragma unroll
            for (int mf = 0; mf < 2; ++mf) {
                const int row = wm * 32 + mf * 16 + lr;
                const int kb  = ks * 4 + lk;
                ah[mf] = *(const f16x8*)&Ash[row * 64 + ((kb ^ (row & 7)) << 3)];
            }
            #pragma unroll
            for (int nf = 0; nf < 4; ++nf) {
                const int row = wn * 64 + nf * 16 + lr;
                const int kb  = ks * 4 + lk;
                const f16x8 bh = *(const f16x8*)&Bsh[row * 64 + ((kb ^ (row & 7)) << 3)];
                #pragma unroll
                for (int mf = 0; mf < 2; ++mf)
                    acc0[mf][nf] = __builtin_amdgcn_mfma_f32_16x16x32_f16(
                        ah[mf], bh, acc0[mf][nf], 0, 0, 0);
            }
        }
        __syncthreads();
    }

    float bv[4];
    #pragma unroll
    for (int nf = 0; nf < 4; ++nf)
        bv[nf] = bias[n0 + wn * 64 + nf * 16 + lr];
    #pragma unroll
    for (int mf = 0; mf < 2; ++mf)
        #pragma unroll
        for (int nf = 0; nf < 4; ++nf)
            #pragma unroll
            for (int r = 0; r < 4; ++r) {
                const int m = m0 + wm * 32 + mf * 16 + lk * 4 + r;
                const int n = n0 + wn * 64 + nf * 16 + lr;
                float x = acc0[mf][nf][r] + bv[nf];
                x = fmaxf(x, 0.f);
                const f16 hcv = (f16)x;
                Ch[(size_t)m * N + n] = __builtin_bit_cast(ushort_t, hcv);
            }
}

// ---------------------------------------------------------------------------
__global__ __launch_bounds__(256)
void tsplit2_kernel(const float* __restrict__ in, ushort_t* __restrict__ t0,
                    ushort_t* __restrict__ t1, int K, int N)
{
    __shared__ float tile[32][33];
    const int t = threadIdx.x;
    const int bk = blockIdx.x * 32, bn = blockIdx.y * 32;
    const int c = t & 31, rb = t >> 5;
    #pragma unroll
    for (int i = 0; i < 4; ++i) {
        const int r = rb + i * 8;
        tile[r][c] = in[(size_t)(bk + r) * N + bn + c];
    }
    __syncthreads();
    #pragma unroll
    for (int i = 0; i < 4; ++i) {
        const int rr = rb + i * 8;
        const float x = tile[c][rr];
        const f16 hv = (f16)x;
        const f16 lv = (f16)((x - (float)hv) * 2048.0f);
        const size_t o = (size_t)(bn + rr) * K + bk + c;
        t0[o] = __builtin_bit_cast(ushort_t, hv);
        t1[o] = __builtin_bit_cast(ushort_t, lv);
    }
}

// ---------------------------------------------------------------------------
__global__ __launch_bounds__(256)
void gemm_trans_kernel(const float* __restrict__ A, const float* __restrict__ Bm,
                       float* __restrict__ C, int M, int KA, int N)
{
    constexpr int BK = 16;
    __shared__ float Asb[BK][64 + 4];
    __shared__ float Bsb[BK][64 + 4];
    const int tid = threadIdx.x;
    const int tx = tid & 15, ty = tid >> 4;
    const int m0 = blockIdx.y * 64, n0 = blockIdx.x * 64;

    float acc[4][4] = {};
    const int lr = tid >> 2, lc = (tid & 3) << 2;
    const int kr = tid >> 4, nc = (tid & 15) << 2;

    for (int k0 = 0; k0 < KA; k0 += BK) {
        const float4 a4 = *reinterpret_cast<const float4*>(A + (size_t)(m0 + lr) * KA + k0 + lc);
        const float4 b4 = *reinterpret_cast<const float4*>(Bm + (size_t)(k0 + kr) * N + n0 + nc);
        Asb[lc + 0][lr] = a4.x; Asb[lc + 1][lr] = a4.y;
        Asb[lc + 2][lr] = a4.z; Asb[lc + 3][lr] = a4.w;
        *reinterpret_cast<float4*>(&Bsb[kr][nc]) = b4;
        __syncthreads();
        #pragma unroll
        for (int kk = 0; kk < BK; ++kk) {
            const float4 av = *reinterpret_cast<const float4*>(&Asb[kk][ty << 2]);
            const float4 bv = *reinterpret_cast<const float4*>(&Bsb[kk][tx << 2]);
            const float a[4] = {av.x, av.y, av.z, av.w};
            const float b[4] = {bv.x, bv.y, bv.z, bv.w};
            #pragma unroll
            for (int i = 0; i < 4; ++i)
                #pragma unroll
                for (int j = 0; j < 4; ++j)
                    acc[i][j] = fmaf(a[i], b[j], acc[i][j]);
        }
        __syncthreads();
    }
    #pragma unroll
    for (int i = 0; i < 4; ++i) {
        const int m = m0 + (ty << 2) + i;
        const int b = m >> 12, s = m & (S_ - 1);
        #pragma unroll
        for (int j = 0; j < 4; ++j) {
            const int n = n0 + (tx << 2) + j;
            C[(size_t)(b * N + n) * S_ + s] = acc[i][j];
        }
    }
}

// ---------------------------------------------------------------------------
__global__ __launch_bounds__(256)
void var_kernel(const float* __restrict__ rmvT, float* __restrict__ hvars)
{
    const int bk = blockIdx.x;
    const float* src = rmvT + (size_t)bk * S_;
    float s1 = 0.f, s2 = 0.f;
    for (int t = threadIdx.x; t < S_; t += 256) {
        const float v = src[t];
        s1 += v; s2 += v * v;
    }
    #pragma unroll
    for (int off = 32; off; off >>= 1) {
        s1 += __shfl_xor(s1, off);
        s2 += __shfl_xor(s2, off);
    }
    __shared__ float r1[4], r2[4];
    const int wave = threadIdx.x >> 6, lane = threadIdx.x & 63;
    if (lane == 0) { r1[wave] = s1; r2[wave] = s2; }
    __syncthreads();
    if (threadIdx.x == 0) {
        const float t1 = r1[0] + r1[1] + r1[2] + r1[3];
        const float t2 = r2[0] + r2[1] + r2[2] + r2[3];
        const float mu = t1 / (float)S_;
        hvars[bk] = t2 / (float)S_ - mu * mu;
    }
}

__global__ void topk_kernel(const float* __restrict__ hvars, int* __restrict__ topidx)
{
    const int b = threadIdx.x;
    if (b >= B_) return;
    float v[KK];
    for (int k = 0; k < KK; ++k) v[k] = hvars[b * KK + k];
    for (int i = 0; i < KH; ++i) {
        int best = 0; float bv = -3.4e38f;
        for (int k = 0; k < KK; ++k)
            if (v[k] > bv) { bv = v[k]; best = k; }
        topidx[b * KH + i] = best;
        v[best] = -3.4e38f;
    }
}

// ---------------------------------------------------------------------------
__global__ __launch_bounds__(256)
void rank_kernel(const float* __restrict__ rmvT, const int* __restrict__ topidx,
                 int* __restrict__ gidx)
{
    const int bi = blockIdx.x;
    const int b = bi >> 2, ih = bi & 3;
    const int k = topidx[b * KH + ih];
    const float* src = rmvT + (size_t)(b * KK + k) * S_;
    __shared__ __align__(16) unsigned long long keys[S_];
    __shared__ int partial[4][64];
    for (int t = threadIdx.x; t < S_; t += 256) {
        const unsigned bits = __builtin_bit_cast(unsigned, src[t]);
        const unsigned u = (bits & 0x80000000u) ? ~bits : (bits | 0x80000000u);
        keys[t] = ((unsigned long long)u << 12) | (unsigned)t;
    }
    __syncthreads();

    const int il = threadIdx.x & 63;
    const int chunk = threadIdx.x >> 6;
    const int i = blockIdx.y * 64 + il;
    const unsigned long long ki = keys[i];

    int cnt = 0;
    const int jbase = chunk << 10;
    #pragma unroll 8
    for (int jj = 0; jj < 1024; jj += 2) {
        const ulonglong2 k2 = *reinterpret_cast<const ulonglong2*>(&keys[jbase + jj]);
        cnt += (int)(k2.x < ki);
        cnt += (int)(k2.y < ki);
    }
    partial[chunk][il] = cnt;
    __syncthreads();
    if (threadIdx.x < 64) {
        const int rank = partial[0][threadIdx.x] + partial[1][threadIdx.x]
                       + partial[2][threadIdx.x] + partial[3][threadIdx.x];
        const int ii = blockIdx.y * 64 + threadIdx.x;
        gidx[((b << 12) + rank) * KH + ih] = (b << 12) + ii;
    }
}

// ---------------------------------------------------------------------------
// Barrier-free fused scores + window sum + residual + LayerNorm (f16 q2h).
// ---------------------------------------------------------------------------
__global__ __launch_bounds__(256)
void final_kernel(const ushort_t* __restrict__ vh, const ushort_t* __restrict__ q2h,
                  const float* __restrict__ inputs, const float* __restrict__ gamma,
                  const float* __restrict__ beta, float* __restrict__ out)
{
    const int bid = blockIdx.x;                            // 4096 blocks
    const int m0 = (((bid & 7) << 9) | (bid >> 3)) << 2;   // XCD swizzle, 4 rows
    const int wave = threadIdx.x >> 6, lane = threadIdx.x & 63;
    const int m = m0 + wave;
    const int s = m & (S_ - 1), b = m >> 12;
    const int jb = (s < 4) ? 0 : (s >= S_ - 4 ? S_ - WW : s - 4);

    const ushort_t* vb = vh + (size_t)(b * S_ + jb) * DH;
    const float* inp = inputs + (size_t)m * DH;
    f16x8 varr[2][WW];
    float4 iv[2][2];
    #pragma unroll
    for (int c = 0; c < 2; ++c) {
        const int h = (c << 9) + (lane << 3);
        #pragma unroll
        for (int w = 0; w < WW; ++w)
            varr[c][w] = *reinterpret_cast<const f16x8*>(vb + (size_t)w * DH + h);
        iv[c][0] = *reinterpret_cast<const float4*>(inp + h);
        iv[c][1] = *reinterpret_cast<const float4*>(inp + h + 4);
    }

    const ushort4 qv4 = *reinterpret_cast<const ushort4*>(q2h + (size_t)m * DL + (lane << 2));
    const float qx = (float)__builtin_bit_cast(f16, qv4.x);
    const float qy = (float)__builtin_bit_cast(f16, qv4.y);
    const float qz = (float)__builtin_bit_cast(f16, qv4.z);
    const float qw = (float)__builtin_bit_cast(f16, qv4.w);
    const ushort_t* kbase = q2h + (size_t)(b * S_ + jb) * DL;
    float sc[WW];
    #pragma unroll
    for (int w = 0; w < WW; ++w) {
        const ushort4 kv4 = *reinterpret_cast<const ushort4*>(kbase + w * DL + (lane << 2));
        float d = qx * (float)__builtin_bit_cast(f16, kv4.x)
                + qy * (float)__builtin_bit_cast(f16, kv4.y)
                + qz * (float)__builtin_bit_cast(f16, kv4.z)
                + qw * (float)__builtin_bit_cast(f16, kv4.w);
        #pragma unroll
        for (int off = 32; off; off >>= 1) d += __shfl_xor(d, off);
        sc[w] = d * 0.0625f;
    }
    float mx = sc[0];
    #pragma unroll
    for (int w = 1; w < WW; ++w) mx = fmaxf(mx, sc[w]);
    float wgt[WW]; float sum = 0.f;
    #pragma unroll
    for (int w = 0; w < WW; ++w) { wgt[w] = __expf(sc[w] - mx); sum += wgt[w]; }
    const float inv = 1.f / sum;
    #pragma unroll
    for (int w = 0; w < WW; ++w) wgt[w] *= inv;

    float x[2][8];
    float s1 = 0.f, s2 = 0.f;
    #pragma unroll
    for (int c = 0; c < 2; ++c) {
        float acc[8] = {};
        #pragma unroll
        for (int w = 0; w < WW; ++w) {
            const f16x8 vv = varr[c][w];
            #pragma unroll
            for (int e = 0; e < 8; ++e)
                acc[e] = fmaf(wgt[w], (float)vv[e], acc[e]);
        }
        #pragma unroll
        for (int e = 0; e < 8; ++e) {
            const float ivv = (e < 4) ? (&iv[c][0].x)[e] : (&iv[c][1].x)[e - 4];
            acc[e] += ivv;
            x[c][e] = acc[e];
            s1 += acc[e];
            s2 += acc[e] * acc[e];
        }
    }

    #pragma unroll
    for (int off = 32; off; off >>= 1) {
        s1 += __shfl_xor(s1, off);
        s2 += __shfl_xor(s2, off);
    }
    const float mu = s1 / (float)DH;
    const float rs = rsqrtf(s2 / (float)DH - mu * mu + 0.001f);

    #pragma unroll
    for (int c = 0; c < 2; ++c) {
        const int h = (c << 9) + (lane << 3);
        #pragma unroll
        for (int half = 0; half < 2; ++half) {
            const float4 g  = *reinterpret_cast<const float4*>(gamma + h + half * 4);
            const float4 bt = *reinterpret_cast<const float4*>(beta + h + half * 4);
            float4 o;
            o.x = g.x * (x[c][half * 4 + 0] - mu) * rs + bt.x;
            o.y = g.y * (x[c][half * 4 + 1] - mu) * rs + bt.y;
            o.z = g.z * (x[c][half * 4 + 2] - mu) * rs + bt.z;
            o.w = g.w * (x[c][half * 4 + 3] - mu) * rs + bt.w;
            *reinterpret_cast<float4*>(out + (size_t)m * DH + h + half * 4) = o;
        }
    }
}

// ---------------------------------------------------------------------------
extern "C" void kernel_launch(void* const* d_in, const int* in_sizes, int n_in,
                              void* d_out, int out_size, void* d_ws, size_t ws_size,
                              hipStream_t stream)
{
    (void)in_sizes; (void)n_in; (void)out_size; (void)ws_size;
    const float* inputs = (const float*)d_in[0];
    const float* W1     = (const float*)d_in[1];
    const float* b1     = (const float*)d_in[2];
    const float* RME    = (const float*)d_in[3];
    const float* K2     = (const float*)d_in[4];
    const float* b2     = (const float*)d_in[5];
    const float* Wu     = (const float*)d_in[6];
    const float* bu     = (const float*)d_in[7];
    const float* gamma  = (const float*)d_in[8];
    const float* beta   = (const float*)d_in[9];
    float* out = (float*)d_out;

    char* ws = (char*)d_ws;
    const size_t MB = 1u << 20;
    ushort_t* vh  = (ushort_t*)(ws + 0 * MB);      // 32MB f16 v
    float*    q   = (float*)   (ws + 64 * MB);     // 16MB
    ushort_t* qh  = (ushort_t*)(ws + 80 * MB);     // 8MB
    ushort_t* ql  = (ushort_t*)(ws + 88 * MB);     // 8MB
    ushort_t* q2h = (ushort_t*)(ws + 112 * MB);    // 8MB
    float*    rmvT= (float*)   (ws + 128 * MB);    // 4MB
    float*    hvars  = (float*)(ws + 132 * MB);
    int*      topidx = (int*)  (ws + 132 * MB + 4096);
    int*      gidx   = (int*)  (ws + 132 * MB + 8192);   // 256KB
    ushort_t* w1th = (ushort_t*)(ws + 133 * MB);
    ushort_t* w1tl = w1th + (DH * DL);
    ushort_t* k2th = w1tl + (DH * DL);
    ushort_t* k2tl = k2th + (KH * DL * DL);
    ushort_t* wuth = k2tl + (KH * DL * DL);
    ushort_t* wutl = wuth + (DL * DH);

    const int M = B_ * S_;

    // 0. transpose+split weights (tiny)
    tsplit2_kernel<<<dim3(DH / 32, DL / 32), dim3(256), 0, stream>>>(W1, w1th, w1tl, DH, DL);
    tsplit2_kernel<<<dim3(KH * DL / 32, DL / 32), dim3(256), 0, stream>>>((const float*)K2, k2th, k2tl, KH * DL, DL);
    tsplit2_kernel<<<dim3(DL / 32, DH / 32), dim3(256), 0, stream>>>(Wu, wuth, wutl, DL, DH);

    // 1. q = relu(inputs @ W1 + b1) — A-direct regs, counted-vmcnt B pipeline
    gemm_adirect<true, false, 1, DH><<<dim3((DL / 64) * (M / 64)), dim3(256), 0, stream>>>(
        inputs, nullptr, nullptr, w1th, w1tl, b1, q, qh, ql, nullptr, DL, DL / 64);
    // 2. RMVsT[b][k][s] = (q @ RME)^T  (fp32, key path)
    gemm_trans_kernel<<<dim3(KK / 64, M / 64), dim3(256), 0, stream>>>(q, RME, rmvT, M, DL, KK);
    // 3-5. variance, top-4 heads, u64 rank argsort -> gather table
    var_kernel<<<dim3(B_ * KK), dim3(256), 0, stream>>>(rmvT, hvars);
    topk_kernel<<<dim3(1), dim3(64), 0, stream>>>(hvars, topidx);
    rank_kernel<<<dim3(B_ * KH, S_ / 64), dim3(256), 0, stream>>>(rmvT, topidx, gidx);
    // 6. q2h = f16(relu(gather(q) @ K2 + b2)) — A-direct per-lane gather
    gemm_adirect<false, true, 2, KH * DL><<<dim3((DL / 64) * (M / 64)), dim3(256), 0, stream>>>(
        nullptr, qh, ql, k2th, k2tl, b2, nullptr, q2h, nullptr, gidx, DL, DL / 64);
    // 7. v = relu(q2 @ Wu + bu) — 1-limb 128x128, f16 out
    mfma_gemm1l<<<dim3((DH / 128) * (M / 128)), dim3(512), 0, stream>>>(
        q2h, wuth, bu, vh, DL, DH, DH / 128);
    // 8+9. barrier-free fused scores + window sum + residual + LayerNorm
    final_kernel<<<dim3(M / 4), dim3(256), 0, stream>>>(vh, q2h, inputs, gamma, beta, out);
}

// Round 20
// 179.202 us; speedup vs baseline: 1.4808x; 1.4808x over previous
//
#include <hip/hip_runtime.h>

#define B_  4
#define S_  4096
#define DH  1024
#define DL  256
#define KK  64
#define KH  4
#define WW  9

typedef unsigned short ushort_t;
typedef _Float16 f16;
typedef _Float16 f16x8 __attribute__((ext_vector_type(8)));
typedef float  f32x4  __attribute__((ext_vector_type(4)));

__device__ __forceinline__ void gld_lds16(const void* g, void* lds_uniform_base) {
    __builtin_amdgcn_global_load_lds(
        (const __attribute__((address_space(1))) unsigned int*)g,
        (__attribute__((address_space(3))) unsigned int*)lds_uniform_base,
        16, 0, 0);
}

// ---------------------------------------------------------------------------
// 2-limb fp16 MFMA GEMM, 64x128 tile, BK=64, 256 threads / 4 waves (2x2,
// wave tile 32x64).  r13-measured best (63 µs class) among 7 structural
// variants (64², 128², dbuf, counted-vmcnt, A-direct all ≥ this).
//   acc0 += ah*bh ;  acc1 += ah*bl + al*bh ;  x = acc0 + acc1/2048 + bias
// AFP32: A raw fp32, staged fp32, limb-split in-register (bit-identical to a
// pre-split).  GATHER: A row r of head (k0>>8) from Ah/Al[gidx[...]].
// OUTMODE 1: fp32 C + f16 h/l limbs.  OUTMODE 2: f16 Ch only.
// 1-D grid, bijective XCD swizzle (gridDim.x % 8 == 0).
// ---------------------------------------------------------------------------
template<bool AFP32, bool GATHER, int OUTMODE>
__global__ __launch_bounds__(256)
void mfma_gemm2(const float* __restrict__ Af,
                const ushort_t* __restrict__ Ah, const ushort_t* __restrict__ Al,
                const ushort_t* __restrict__ Bh, const ushort_t* __restrict__ Bl,
                const float* __restrict__ bias, float* __restrict__ C,
                ushort_t* __restrict__ Ch, ushort_t* __restrict__ Cl,
                const int* __restrict__ gidx, int K, int N, int nbx)
{
    __shared__ __align__(16) ushort_t Abuf[64 * 64 * 2];   // 16 KB (fp32 tile OR 2 limb tiles)
    __shared__ __align__(16) ushort_t Bsh[128 * 64];       // 16 KB
    __shared__ __align__(16) ushort_t Bsl[128 * 64];       // 16 KB

    const int tid = threadIdx.x;
    const int w = tid >> 6, l = tid & 63;
    const int wm = w >> 1, wn = w & 1;
    const int lr = l & 15, lk = l >> 4;
    const int cpx = gridDim.x >> 3;
    const int orig = (blockIdx.x & 7) * cpx + (blockIdx.x >> 3);
    const int m0 = (orig / nbx) * 64, n0 = (orig % nbx) * 128;

    f32x4 acc0[2][4] = {};
    f32x4 acc1[2][4] = {};

    for (int k0 = 0; k0 < K; k0 += 64) {
        if (AFP32) {
            // stage fp32 A tile 64x64 (16 KB = 1024 16B-chunks, 4/thread)
            float* Asf = (float*)Abuf;
            #pragma unroll
            for (int it = 0; it < 4; ++it) {
                const int c = it * 256 + tid;
                const int r = c >> 4, cc = c & 15;
                const int cs = cc ^ ((r & 7) << 1);
                const float* src = Af + (size_t)(m0 + r) * K + k0 + cs * 4;
                gld_lds16(src, &Asf[(size_t)c * 4]);
            }
        } else {
            ushort_t* Ash = Abuf;
            ushort_t* Asl = Abuf + 64 * 64;
            #pragma unroll
            for (int it = 0; it < 2; ++it) {
                const int c = it * 256 + tid;
                const int r = c >> 3, kp = c & 7;
                const int kl = kp ^ (r & 7);
                size_t off;
                if (GATHER) {
                    const int rg = gidx[(m0 + r) * KH + (k0 >> 8)];
                    off = (size_t)rg * DL + (k0 & (DL - 1)) + kl * 8;
                } else {
                    off = (size_t)(m0 + r) * K + k0 + kl * 8;
                }
                gld_lds16(Ah + off, &Ash[(size_t)c * 8]);
                gld_lds16(Al + off, &Asl[(size_t)c * 8]);
            }
        }
        #pragma unroll
        for (int it = 0; it < 4; ++it) {
            const int c = it * 256 + tid;
            const int r = c >> 3, kp = c & 7;
            const int kl = kp ^ (r & 7);
            const size_t off = (size_t)(n0 + r) * K + k0 + kl * 8;
            gld_lds16(Bh + off, &Bsh[(size_t)c * 8]);
            gld_lds16(Bl + off, &Bsl[(size_t)c * 8]);
        }
        __syncthreads();

        #pragma unroll
        for (int ks = 0; ks < 2; ++ks) {
            f16x8 ah[2], al[2];
            #pragma unroll
            for (int mf = 0; mf < 2; ++mf) {
                const int row = wm * 32 + mf * 16 + lr;
                const int kb  = ks * 4 + lk;
                if (AFP32) {
                    const float* Asf = (const float*)Abuf;
                    const int fo = row * 64 + ((kb ^ (row & 7)) << 3);
                    const f32x4 lo = *(const f32x4*)&Asf[fo];
                    const f32x4 hi = *(const f32x4*)&Asf[fo + 4];
                    const float xs[8] = {lo[0], lo[1], lo[2], lo[3],
                                         hi[0], hi[1], hi[2], hi[3]};
                    #pragma unroll
                    for (int e = 0; e < 8; ++e) {
                        const f16 h = (f16)xs[e];
                        const f16 lv = (f16)((xs[e] - (float)h) * 2048.0f);
                        ah[mf][e] = h;
                        al[mf][e] = lv;
                    }
                } else {
                    const ushort_t* Ash = Abuf;
                    const ushort_t* Asl = Abuf + 64 * 64;
                    const int o = row * 64 + ((kb ^ (row & 7)) << 3);
                    ah[mf] = *(const f16x8*)&Ash[o];
                    al[mf] = *(const f16x8*)&Asl[o];
                }
            }
            #pragma unroll
            for (int nf = 0; nf < 4; ++nf) {
                const int row = wn * 64 + nf * 16 + lr;
                const int kb  = ks * 4 + lk;
                const int o   = row * 64 + ((kb ^ (row & 7)) << 3);
                const f16x8 bh = *(const f16x8*)&Bsh[o];
                const f16x8 bl = *(const f16x8*)&Bsl[o];
                #pragma unroll
                for (int mf = 0; mf < 2; ++mf) {
                    acc0[mf][nf] = __builtin_amdgcn_mfma_f32_16x16x32_f16(
                        ah[mf], bh, acc0[mf][nf], 0, 0, 0);
                    acc1[mf][nf] = __builtin_amdgcn_mfma_f32_16x16x32_f16(
                        ah[mf], bl, acc1[mf][nf], 0, 0, 0);
                    acc1[mf][nf] = __builtin_amdgcn_mfma_f32_16x16x32_f16(
                        al[mf], bh, acc1[mf][nf], 0, 0, 0);
                }
            }
        }
        __syncthreads();
    }

    float bv[4];
    #pragma unroll
    for (int nf = 0; nf < 4; ++nf)
        bv[nf] = bias[n0 + wn * 64 + nf * 16 + lr];
    #pragma unroll
    for (int mf = 0; mf < 2; ++mf)
        #pragma unroll
        for (int nf = 0; nf < 4; ++nf)
            #pragma unroll
            for (int r = 0; r < 4; ++r) {
                const int m = m0 + wm * 32 + mf * 16 + lk * 4 + r;
                const int n = n0 + wn * 64 + nf * 16 + lr;
                float x = acc0[mf][nf][r] + acc1[mf][nf][r] * (1.0f / 2048.0f) + bv[nf];
                x = fmaxf(x, 0.f);
                const f16 h = (f16)x;
                if (OUTMODE == 2) {
                    Ch[(size_t)m * N + n] = __builtin_bit_cast(ushort_t, h);
                } else {
                    C[(size_t)m * N + n] = x;
                    Ch[(size_t)m * N + n] = __builtin_bit_cast(ushort_t, h);
                    const f16 lo = (f16)((x - (float)h) * 2048.0f);
                    Cl[(size_t)m * N + n] = __builtin_bit_cast(ushort_t, lo);
                }
            }
}

// ---------------------------------------------------------------------------
// 1-limb fp16 GEMM for v = relu(q2 @ Wu + bu): 128x128 tile, 512 threads,
// single-buffer 2-barrier (r17-measured ~15 µs).
// ---------------------------------------------------------------------------
__global__ __launch_bounds__(512)
void mfma_gemm1l(const ushort_t* __restrict__ Ah, const ushort_t* __restrict__ Bh,
                 const float* __restrict__ bias, ushort_t* __restrict__ Ch,
                 int K, int N, int nbx)
{
    __shared__ __align__(16) ushort_t Ash[128 * 64];   // 16KB
    __shared__ __align__(16) ushort_t Bsh[128 * 64];   // 16KB

    const int tid = threadIdx.x;
    const int w = tid >> 6, l = tid & 63;
    const int wm = w >> 1, wn = w & 1;          // 4m x 2n wave grid
    const int lr = l & 15, lk = l >> 4;
    const int cpx = gridDim.x >> 3;
    const int orig = (blockIdx.x & 7) * cpx + (blockIdx.x >> 3);
    const int m0 = (orig / nbx) * 128, n0 = (orig % nbx) * 128;

    f32x4 acc0[2][4] = {};

    for (int k0 = 0; k0 < K; k0 += 64) {
        #pragma unroll
        for (int it = 0; it < 2; ++it) {
            const int c = it * 512 + tid;       // 0..1023
            const int r = c >> 3, kp = c & 7;
            const int kl = kp ^ (r & 7);
            const size_t offA = (size_t)(m0 + r) * K + k0 + kl * 8;
            const size_t offB = (size_t)(n0 + r) * K + k0 + kl * 8;
            gld_lds16(Ah + offA, &Ash[(size_t)c * 8]);
            gld_lds16(Bh + offB, &Bsh[(size_t)c * 8]);
        }
        __syncthreads();

        #pragma unroll
        for (int ks = 0; ks < 2; ++ks) {
            f16x8 ah[2];
            #pragma unroll
            for (int mf = 0; mf < 2; ++mf) {
                const int row = wm * 32 + mf * 16 + lr;
                const int kb  = ks * 4 + lk;
                ah[mf] = *(const f16x8*)&Ash[row * 64 + ((kb ^ (row & 7)) << 3)];
            }
            #pragma unroll
            for (int nf = 0; nf < 4; ++nf) {
                const int row = wn * 64 + nf * 16 + lr;
                const int kb  = ks * 4 + lk;
                const f16x8 bh = *(const f16x8*)&Bsh[row * 64 + ((kb ^ (row & 7)) << 3)];
                #pragma unroll
                for (int mf = 0; mf < 2; ++mf)
                    acc0[mf][nf] = __builtin_amdgcn_mfma_f32_16x16x32_f16(
                        ah[mf], bh, acc0[mf][nf], 0, 0, 0);
            }
        }
        __syncthreads();
    }

    float bv[4];
    #pragma unroll
    for (int nf = 0; nf < 4; ++nf)
        bv[nf] = bias[n0 + wn * 64 + nf * 16 + lr];
    #pragma unroll
    for (int mf = 0; mf < 2; ++mf)
        #pragma unroll
        for (int nf = 0; nf < 4; ++nf)
            #pragma unroll
            for (int r = 0; r < 4; ++r) {
                const int m = m0 + wm * 32 + mf * 16 + lk * 4 + r;
                const int n = n0 + wn * 64 + nf * 16 + lr;
                float x = acc0[mf][nf][r] + bv[nf];
                x = fmaxf(x, 0.f);
                const f16 hcv = (f16)x;
                Ch[(size_t)m * N + n] = __builtin_bit_cast(ushort_t, hcv);
            }
}

// ---------------------------------------------------------------------------
__global__ __launch_bounds__(256)
void tsplit2_kernel(const float* __restrict__ in, ushort_t* __restrict__ t0,
                    ushort_t* __restrict__ t1, int K, int N)
{
    __shared__ float tile[32][33];
    const int t = threadIdx.x;
    const int bk = blockIdx.x * 32, bn = blockIdx.y * 32;
    const int c = t & 31, rb = t >> 5;
    #pragma unroll
    for (int i = 0; i < 4; ++i) {
        const int r = rb + i * 8;
        tile[r][c] = in[(size_t)(bk + r) * N + bn + c];
    }
    __syncthreads();
    #pragma unroll
    for (int i = 0; i < 4; ++i) {
        const int rr = rb + i * 8;
        const float x = tile[c][rr];
        const f16 hv = (f16)x;
        const f16 lv = (f16)((x - (float)hv) * 2048.0f);
        const size_t o = (size_t)(bn + rr) * K + bk + c;
        t0[o] = __builtin_bit_cast(ushort_t, hv);
        t1[o] = __builtin_bit_cast(ushort_t, lv);
    }
}

// ---------------------------------------------------------------------------
__global__ __launch_bounds__(256)
void gemm_trans_kernel(const float* __restrict__ A, const float* __restrict__ Bm,
                       float* __restrict__ C, int M, int KA, int N)
{
    constexpr int BK = 16;
    __shared__ float Asb[BK][64 + 4];
    __shared__ float Bsb[BK][64 + 4];
    const int tid = threadIdx.x;
    const int tx = tid & 15, ty = tid >> 4;
    const int m0 = blockIdx.y * 64, n0 = blockIdx.x * 64;

    float acc[4][4] = {};
    const int lr = tid >> 2, lc = (tid & 3) << 2;
    const int kr = tid >> 4, nc = (tid & 15) << 2;

    for (int k0 = 0; k0 < KA; k0 += BK) {
        const float4 a4 = *reinterpret_cast<const float4*>(A + (size_t)(m0 + lr) * KA + k0 + lc);
        const float4 b4 = *reinterpret_cast<const float4*>(Bm + (size_t)(k0 + kr) * N + n0 + nc);
        Asb[lc + 0][lr] = a4.x; Asb[lc + 1][lr] = a4.y;
        Asb[lc + 2][lr] = a4.z; Asb[lc + 3][lr] = a4.w;
        *reinterpret_cast<float4*>(&Bsb[kr][nc]) = b4;
        __syncthreads();
        #pragma unroll
        for (int kk = 0; kk < BK; ++kk) {
            const float4 av = *reinterpret_cast<const float4*>(&Asb[kk][ty << 2]);
            const float4 bv = *reinterpret_cast<const float4*>(&Bsb[kk][tx << 2]);
            const float a[4] = {av.x, av.y, av.z, av.w};
            const float b[4] = {bv.x, bv.y, bv.z, bv.w};
            #pragma unroll
            for (int i = 0; i < 4; ++i)
                #pragma unroll
                for (int j = 0; j < 4; ++j)
                    acc[i][j] = fmaf(a[i], b[j], acc[i][j]);
        }
        __syncthreads();
    }
    #pragma unroll
    for (int i = 0; i < 4; ++i) {
        const int m = m0 + (ty << 2) + i;
        const int b = m >> 12, s = m & (S_ - 1);
        #pragma unroll
        for (int j = 0; j < 4; ++j) {
            const int n = n0 + (tx << 2) + j;
            C[(size_t)(b * N + n) * S_ + s] = acc[i][j];
        }
    }
}

// ---------------------------------------------------------------------------
__global__ __launch_bounds__(256)
void var_kernel(const float* __restrict__ rmvT, float* __restrict__ hvars)
{
    const int bk = blockIdx.x;
    const float* src = rmvT + (size_t)bk * S_;
    float s1 = 0.f, s2 = 0.f;
    for (int t = threadIdx.x; t < S_; t += 256) {
        const float v = src[t];
        s1 += v; s2 += v * v;
    }
    #pragma unroll
    for (int off = 32; off; off >>= 1) {
        s1 += __shfl_xor(s1, off);
        s2 += __shfl_xor(s2, off);
    }
    __shared__ float r1[4], r2[4];
    const int wave = threadIdx.x >> 6, lane = threadIdx.x & 63;
    if (lane == 0) { r1[wave] = s1; r2[wave] = s2; }
    __syncthreads();
    if (threadIdx.x == 0) {
        const float t1 = r1[0] + r1[1] + r1[2] + r1[3];
        const float t2 = r2[0] + r2[1] + r2[2] + r2[3];
        const float mu = t1 / (float)S_;
        hvars[bk] = t2 / (float)S_ - mu * mu;
    }
}

__global__ void topk_kernel(const float* __restrict__ hvars, int* __restrict__ topidx)
{
    const int b = threadIdx.x;
    if (b >= B_) return;
    float v[KK];
    for (int k = 0; k < KK; ++k) v[k] = hvars[b * KK + k];
    for (int i = 0; i < KH; ++i) {
        int best = 0; float bv = -3.4e38f;
        for (int k = 0; k < KK; ++k)
            if (v[k] > bv) { bv = v[k]; best = k; }
        topidx[b * KH + i] = best;
        v[best] = -3.4e38f;
    }
}

// ---------------------------------------------------------------------------
__global__ __launch_bounds__(256)
void rank_kernel(const float* __restrict__ rmvT, const int* __restrict__ topidx,
                 int* __restrict__ gidx)
{
    const int bi = blockIdx.x;
    const int b = bi >> 2, ih = bi & 3;
    const int k = topidx[b * KH + ih];
    const float* src = rmvT + (size_t)(b * KK + k) * S_;
    __shared__ __align__(16) unsigned long long keys[S_];
    __shared__ int partial[4][64];
    for (int t = threadIdx.x; t < S_; t += 256) {
        const unsigned bits = __builtin_bit_cast(unsigned, src[t]);
        const unsigned u = (bits & 0x80000000u) ? ~bits : (bits | 0x80000000u);
        keys[t] = ((unsigned long long)u << 12) | (unsigned)t;
    }
    __syncthreads();

    const int il = threadIdx.x & 63;
    const int chunk = threadIdx.x >> 6;
    const int i = blockIdx.y * 64 + il;
    const unsigned long long ki = keys[i];

    int cnt = 0;
    const int jbase = chunk << 10;
    #pragma unroll 8
    for (int jj = 0; jj < 1024; jj += 2) {
        const ulonglong2 k2 = *reinterpret_cast<const ulonglong2*>(&keys[jbase + jj]);
        cnt += (int)(k2.x < ki);
        cnt += (int)(k2.y < ki);
    }
    partial[chunk][il] = cnt;
    __syncthreads();
    if (threadIdx.x < 64) {
        const int rank = partial[0][threadIdx.x] + partial[1][threadIdx.x]
                       + partial[2][threadIdx.x] + partial[3][threadIdx.x];
        const int ii = blockIdx.y * 64 + threadIdx.x;
        gidx[((b << 12) + rank) * KH + ih] = (b << 12) + ii;
    }
}

// ---------------------------------------------------------------------------
// Barrier-free fused scores + window sum + residual + LayerNorm (f16 q2h).
// ---------------------------------------------------------------------------
__global__ __launch_bounds__(256)
void final_kernel(const ushort_t* __restrict__ vh, const ushort_t* __restrict__ q2h,
                  const float* __restrict__ inputs, const float* __restrict__ gamma,
                  const float* __restrict__ beta, float* __restrict__ out)
{
    const int bid = blockIdx.x;                            // 4096 blocks
    const int m0 = (((bid & 7) << 9) | (bid >> 3)) << 2;   // XCD swizzle, 4 rows
    const int wave = threadIdx.x >> 6, lane = threadIdx.x & 63;
    const int m = m0 + wave;
    const int s = m & (S_ - 1), b = m >> 12;
    const int jb = (s < 4) ? 0 : (s >= S_ - 4 ? S_ - WW : s - 4);

    const ushort_t* vb = vh + (size_t)(b * S_ + jb) * DH;
    const float* inp = inputs + (size_t)m * DH;
    f16x8 varr[2][WW];
    float4 iv[2][2];
    #pragma unroll
    for (int c = 0; c < 2; ++c) {
        const int h = (c << 9) + (lane << 3);
        #pragma unroll
        for (int w = 0; w < WW; ++w)
            varr[c][w] = *reinterpret_cast<const f16x8*>(vb + (size_t)w * DH + h);
        iv[c][0] = *reinterpret_cast<const float4*>(inp + h);
        iv[c][1] = *reinterpret_cast<const float4*>(inp + h + 4);
    }

    const ushort4 qv4 = *reinterpret_cast<const ushort4*>(q2h + (size_t)m * DL + (lane << 2));
    const float qx = (float)__builtin_bit_cast(f16, qv4.x);
    const float qy = (float)__builtin_bit_cast(f16, qv4.y);
    const float qz = (float)__builtin_bit_cast(f16, qv4.z);
    const float qw = (float)__builtin_bit_cast(f16, qv4.w);
    const ushort_t* kbase = q2h + (size_t)(b * S_ + jb) * DL;
    float sc[WW];
    #pragma unroll
    for (int w = 0; w < WW; ++w) {
        const ushort4 kv4 = *reinterpret_cast<const ushort4*>(kbase + w * DL + (lane << 2));
        float d = qx * (float)__builtin_bit_cast(f16, kv4.x)
                + qy * (float)__builtin_bit_cast(f16, kv4.y)
                + qz * (float)__builtin_bit_cast(f16, kv4.z)
                + qw * (float)__builtin_bit_cast(f16, kv4.w);
        #pragma unroll
        for (int off = 32; off; off >>= 1) d += __shfl_xor(d, off);
        sc[w] = d * 0.0625f;
    }
    float mx = sc[0];
    #pragma unroll
    for (int w = 1; w < WW; ++w) mx = fmaxf(mx, sc[w]);
    float wgt[WW]; float sum = 0.f;
    #pragma unroll
    for (int w = 0; w < WW; ++w) { wgt[w] = __expf(sc[w] - mx); sum += wgt[w]; }
    const float inv = 1.f / sum;
    #pragma unroll
    for (int w = 0; w < WW; ++w) wgt[w] *= inv;

    float x[2][8];
    float s1 = 0.f, s2 = 0.f;
    #pragma unroll
    for (int c = 0; c < 2; ++c) {
        float acc[8] = {};
        #pragma unroll
        for (int w = 0; w < WW; ++w) {
            const f16x8 vv = varr[c][w];
            #pragma unroll
            for (int e = 0; e < 8; ++e)
                acc[e] = fmaf(wgt[w], (float)vv[e], acc[e]);
        }
        #pragma unroll
        for (int e = 0; e < 8; ++e) {
            const float ivv = (e < 4) ? (&iv[c][0].x)[e] : (&iv[c][1].x)[e - 4];
            acc[e] += ivv;
            x[c][e] = acc[e];
            s1 += acc[e];
            s2 += acc[e] * acc[e];
        }
    }

    #pragma unroll
    for (int off = 32; off; off >>= 1) {
        s1 += __shfl_xor(s1, off);
        s2 += __shfl_xor(s2, off);
    }
    const float mu = s1 / (float)DH;
    const float rs = rsqrtf(s2 / (float)DH - mu * mu + 0.001f);

    #pragma unroll
    for (int c = 0; c < 2; ++c) {
        const int h = (c << 9) + (lane << 3);
        #pragma unroll
        for (int half = 0; half < 2; ++half) {
            const float4 g  = *reinterpret_cast<const float4*>(gamma + h + half * 4);
            const float4 bt = *reinterpret_cast<const float4*>(beta + h + half * 4);
            float4 o;
            o.x = g.x * (x[c][half * 4 + 0] - mu) * rs + bt.x;
            o.y = g.y * (x[c][half * 4 + 1] - mu) * rs + bt.y;
            o.z = g.z * (x[c][half * 4 + 2] - mu) * rs + bt.z;
            o.w = g.w * (x[c][half * 4 + 3] - mu) * rs + bt.w;
            *reinterpret_cast<float4*>(out + (size_t)m * DH + h + half * 4) = o;
        }
    }
}

// ---------------------------------------------------------------------------
extern "C" void kernel_launch(void* const* d_in, const int* in_sizes, int n_in,
                              void* d_out, int out_size, void* d_ws, size_t ws_size,
                              hipStream_t stream)
{
    (void)in_sizes; (void)n_in; (void)out_size; (void)ws_size;
    const float* inputs = (const float*)d_in[0];
    const float* W1     = (const float*)d_in[1];
    const float* b1     = (const float*)d_in[2];
    const float* RME    = (const float*)d_in[3];
    const float* K2     = (const float*)d_in[4];
    const float* b2     = (const float*)d_in[5];
    const float* Wu     = (const float*)d_in[6];
    const float* bu     = (const float*)d_in[7];
    const float* gamma  = (const float*)d_in[8];
    const float* beta   = (const float*)d_in[9];
    float* out = (float*)d_out;

    char* ws = (char*)d_ws;
    const size_t MB = 1u << 20;
    ushort_t* vh  = (ushort_t*)(ws + 0 * MB);      // 32MB f16 v
    float*    q   = (float*)   (ws + 64 * MB);     // 16MB
    ushort_t* qh  = (ushort_t*)(ws + 80 * MB);     // 8MB
    ushort_t* ql  = (ushort_t*)(ws + 88 * MB);     // 8MB
    ushort_t* q2h = (ushort_t*)(ws + 112 * MB);    // 8MB
    float*    rmvT= (float*)   (ws + 128 * MB);    // 4MB
    float*    hvars  = (float*)(ws + 132 * MB);
    int*      topidx = (int*)  (ws + 132 * MB + 4096);
    int*      gidx   = (int*)  (ws + 132 * MB + 8192);   // 256KB
    ushort_t* w1th = (ushort_t*)(ws + 133 * MB);
    ushort_t* w1tl = w1th + (DH * DL);
    ushort_t* k2th = w1tl + (DH * DL);
    ushort_t* k2tl = k2th + (KH * DL * DL);
    ushort_t* wuth = k2tl + (KH * DL * DL);
    ushort_t* wutl = wuth + (DL * DH);

    const int M = B_ * S_;

    // 0. transpose+split weights (tiny)
    tsplit2_kernel<<<dim3(DH / 32, DL / 32), dim3(256), 0, stream>>>(W1, w1th, w1tl, DH, DL);
    tsplit2_kernel<<<dim3(KH * DL / 32, DL / 32), dim3(256), 0, stream>>>((const float*)K2, k2th, k2tl, KH * DL, DL);
    tsplit2_kernel<<<dim3(DL / 32, DH / 32), dim3(256), 0, stream>>>(Wu, wuth, wutl, DL, DH);

    // 1. q = relu(inputs @ W1 + b1) — 64x128 tile (r13 best), in-reg A split
    mfma_gemm2<true, false, 1><<<dim3((DL / 128) * (M / 64)), dim3(256), 0, stream>>>(
        inputs, nullptr, nullptr, w1th, w1tl, b1, q, qh, ql, nullptr, DH, DL, DL / 128);
    // 2. RMVsT[b][k][s] = (q @ RME)^T  (fp32, key path)
    gemm_trans_kernel<<<dim3(KK / 64, M / 64), dim3(256), 0, stream>>>(q, RME, rmvT, M, DL, KK);
    // 3-5. variance, top-4 heads, u64 rank argsort -> gather table
    var_kernel<<<dim3(B_ * KK), dim3(256), 0, stream>>>(rmvT, hvars);
    topk_kernel<<<dim3(1), dim3(64), 0, stream>>>(hvars, topidx);
    rank_kernel<<<dim3(B_ * KH, S_ / 64), dim3(256), 0, stream>>>(rmvT, topidx, gidx);
    // 6. q2h = f16(relu(gather(q) @ K2 + b2)) — 64x128, f16-only output
    mfma_gemm2<false, true, 2><<<dim3((DL / 128) * (M / 64)), dim3(256), 0, stream>>>(
        nullptr, qh, ql, k2th, k2tl, b2, nullptr, q2h, nullptr, gidx, KH * DL, DL, DL / 128);
    // 7. v = relu(q2 @ Wu + bu) — 1-limb 128x128, f16 out (r17 best)
    mfma_gemm1l<<<dim3((DH / 128) * (M / 128)), dim3(512), 0, stream>>>(
        q2h, wuth, bu, vh, DL, DH, DH / 128);
    // 8+9. barrier-free fused scores + window sum + residual + LayerNorm
    final_kernel<<<dim3(M / 4), dim3(256), 0, stream>>>(vh, q2h, inputs, gamma, beta, out);
}

// Round 21
// 165.621 us; speedup vs baseline: 1.6022x; 1.0820x over previous
//
#include <hip/hip_runtime.h>

#define B_  4
#define S_  4096
#define DH  1024
#define DL  256
#define KK  64
#define KH  4
#define WW  9

typedef unsigned short ushort_t;
typedef _Float16 f16;
typedef _Float16 f16x8 __attribute__((ext_vector_type(8)));
typedef float  f32x4  __attribute__((ext_vector_type(4)));

__device__ __forceinline__ void gld_lds16(const void* g, void* lds_uniform_base) {
    __builtin_amdgcn_global_load_lds(
        (const __attribute__((address_space(1))) unsigned int*)g,
        (__attribute__((address_space(3))) unsigned int*)lds_uniform_base,
        16, 0, 0);
}

// ---------------------------------------------------------------------------
// 2-limb fp16 MFMA GEMM, 64x128 tile, BK=64, 256 threads / 4 waves (2x2,
// wave tile 32x64).  r13/r20-measured best 2-limb form (~63 µs).
//   acc0 += ah*bh ;  acc1 += ah*bl + al*bh ;  x = acc0 + acc1/2048 + bias
// A raw fp32, staged fp32, limb-split in-register (bit-identical to a
// pre-split).  Outputs fp32 C + f16 Ch (low limb no longer consumed).
// 1-D grid, bijective XCD swizzle (gridDim.x % 8 == 0).
// ---------------------------------------------------------------------------
__global__ __launch_bounds__(256)
void mfma_gemm2(const float* __restrict__ Af,
                const ushort_t* __restrict__ Bh, const ushort_t* __restrict__ Bl,
                const float* __restrict__ bias, float* __restrict__ C,
                ushort_t* __restrict__ Ch, int K, int N, int nbx)
{
    __shared__ __align__(16) ushort_t Abuf[64 * 64 * 2];   // 16 KB fp32 tile
    __shared__ __align__(16) ushort_t Bsh[128 * 64];       // 16 KB
    __shared__ __align__(16) ushort_t Bsl[128 * 64];       // 16 KB

    const int tid = threadIdx.x;
    const int w = tid >> 6, l = tid & 63;
    const int wm = w >> 1, wn = w & 1;
    const int lr = l & 15, lk = l >> 4;
    const int cpx = gridDim.x >> 3;
    const int orig = (blockIdx.x & 7) * cpx + (blockIdx.x >> 3);
    const int m0 = (orig / nbx) * 64, n0 = (orig % nbx) * 128;

    f32x4 acc0[2][4] = {};
    f32x4 acc1[2][4] = {};

    for (int k0 = 0; k0 < K; k0 += 64) {
        {
            float* Asf = (float*)Abuf;
            #pragma unroll
            for (int it = 0; it < 4; ++it) {
                const int c = it * 256 + tid;
                const int r = c >> 4, cc = c & 15;
                const int cs = cc ^ ((r & 7) << 1);
                const float* src = Af + (size_t)(m0 + r) * K + k0 + cs * 4;
                gld_lds16(src, &Asf[(size_t)c * 4]);
            }
        }
        #pragma unroll
        for (int it = 0; it < 4; ++it) {
            const int c = it * 256 + tid;
            const int r = c >> 3, kp = c & 7;
            const int kl = kp ^ (r & 7);
            const size_t off = (size_t)(n0 + r) * K + k0 + kl * 8;
            gld_lds16(Bh + off, &Bsh[(size_t)c * 8]);
            gld_lds16(Bl + off, &Bsl[(size_t)c * 8]);
        }
        __syncthreads();

        #pragma unroll
        for (int ks = 0; ks < 2; ++ks) {
            f16x8 ah[2], al[2];
            #pragma unroll
            for (int mf = 0; mf < 2; ++mf) {
                const int row = wm * 32 + mf * 16 + lr;
                const int kb  = ks * 4 + lk;
                const float* Asf = (const float*)Abuf;
                const int fo = row * 64 + ((kb ^ (row & 7)) << 3);
                const f32x4 lo = *(const f32x4*)&Asf[fo];
                const f32x4 hi = *(const f32x4*)&Asf[fo + 4];
                const float xs[8] = {lo[0], lo[1], lo[2], lo[3],
                                     hi[0], hi[1], hi[2], hi[3]};
                #pragma unroll
                for (int e = 0; e < 8; ++e) {
                    const f16 h = (f16)xs[e];
                    const f16 lv = (f16)((xs[e] - (float)h) * 2048.0f);
                    ah[mf][e] = h;
                    al[mf][e] = lv;
                }
            }
            #pragma unroll
            for (int nf = 0; nf < 4; ++nf) {
                const int row = wn * 64 + nf * 16 + lr;
                const int kb  = ks * 4 + lk;
                const int o   = row * 64 + ((kb ^ (row & 7)) << 3);
                const f16x8 bh = *(const f16x8*)&Bsh[o];
                const f16x8 bl = *(const f16x8*)&Bsl[o];
                #pragma unroll
                for (int mf = 0; mf < 2; ++mf) {
                    acc0[mf][nf] = __builtin_amdgcn_mfma_f32_16x16x32_f16(
                        ah[mf], bh, acc0[mf][nf], 0, 0, 0);
                    acc1[mf][nf] = __builtin_amdgcn_mfma_f32_16x16x32_f16(
                        ah[mf], bl, acc1[mf][nf], 0, 0, 0);
                    acc1[mf][nf] = __builtin_amdgcn_mfma_f32_16x16x32_f16(
                        al[mf], bh, acc1[mf][nf], 0, 0, 0);
                }
            }
        }
        __syncthreads();
    }

    float bv[4];
    #pragma unroll
    for (int nf = 0; nf < 4; ++nf)
        bv[nf] = bias[n0 + wn * 64 + nf * 16 + lr];
    #pragma unroll
    for (int mf = 0; mf < 2; ++mf)
        #pragma unroll
        for (int nf = 0; nf < 4; ++nf)
            #pragma unroll
            for (int r = 0; r < 4; ++r) {
                const int m = m0 + wm * 32 + mf * 16 + lk * 4 + r;
                const int n = n0 + wn * 64 + nf * 16 + lr;
                float x = acc0[mf][nf][r] + acc1[mf][nf][r] * (1.0f / 2048.0f) + bv[nf];
                x = fmaxf(x, 0.f);
                C[(size_t)m * N + n] = x;
                const f16 h = (f16)x;
                Ch[(size_t)m * N + n] = __builtin_bit_cast(ushort_t, h);
            }
}

// ---------------------------------------------------------------------------
// 1-limb fp16 gather GEMM for q2h = f16(relu(gather(qh) @ K2h + b2)):
// 64x128 tile, 256 threads.  q2 is f16-stored and feeds only the smooth
// softmax/value path, so f16-product accuracy (~6e-4 abs) suffices —
// 2-limb compute then f16 rounding was wasted work (gemm7 1-limb conversion
// measured 40->15 µs for the same change).  Staging 6 gld/k-step (was 12),
// 16 MFMA (was 48), LDS 24 KB.
// ---------------------------------------------------------------------------
__global__ __launch_bounds__(256)
void gemm6_1l(const ushort_t* __restrict__ Ah, const ushort_t* __restrict__ Bh,
              const float* __restrict__ bias, ushort_t* __restrict__ Ch,
              const int* __restrict__ gidx, int K, int N, int nbx)
{
    __shared__ __align__(16) ushort_t Ash[64 * 64];    // 8 KB
    __shared__ __align__(16) ushort_t Bsh[128 * 64];   // 16 KB

    const int tid = threadIdx.x;
    const int w = tid >> 6, l = tid & 63;
    const int wm = w >> 1, wn = w & 1;
    const int lr = l & 15, lk = l >> 4;
    const int cpx = gridDim.x >> 3;
    const int orig = (blockIdx.x & 7) * cpx + (blockIdx.x >> 3);
    const int m0 = (orig / nbx) * 64, n0 = (orig % nbx) * 128;

    f32x4 acc0[2][4] = {};

    for (int k0 = 0; k0 < K; k0 += 64) {
        #pragma unroll
        for (int it = 0; it < 2; ++it) {
            const int c = it * 256 + tid;       // 0..511
            const int r = c >> 3, kp = c & 7;
            const int kl = kp ^ (r & 7);
            const int rg = gidx[(m0 + r) * KH + (k0 >> 8)];
            const size_t off = (size_t)rg * DL + (k0 & (DL - 1)) + kl * 8;
            gld_lds16(Ah + off, &Ash[(size_t)c * 8]);
        }
        #pragma unroll
        for (int it = 0; it < 4; ++it) {
            const int c = it * 256 + tid;
            const int r = c >> 3, kp = c & 7;
            const int kl = kp ^ (r & 7);
            const size_t off = (size_t)(n0 + r) * K + k0 + kl * 8;
            gld_lds16(Bh + off, &Bsh[(size_t)c * 8]);
        }
        __syncthreads();

        #pragma unroll
        for (int ks = 0; ks < 2; ++ks) {
            f16x8 ah[2];
            #pragma unroll
            for (int mf = 0; mf < 2; ++mf) {
                const int row = wm * 32 + mf * 16 + lr;
                const int kb  = ks * 4 + lk;
                ah[mf] = *(const f16x8*)&Ash[row * 64 + ((kb ^ (row & 7)) << 3)];
            }
            #pragma unroll
            for (int nf = 0; nf < 4; ++nf) {
                const int row = wn * 64 + nf * 16 + lr;
                const int kb  = ks * 4 + lk;
                const f16x8 bh = *(const f16x8*)&Bsh[row * 64 + ((kb ^ (row & 7)) << 3)];
                #pragma unroll
                for (int mf = 0; mf < 2; ++mf)
                    acc0[mf][nf] = __builtin_amdgcn_mfma_f32_16x16x32_f16(
                        ah[mf], bh, acc0[mf][nf], 0, 0, 0);
            }
        }
        __syncthreads();
    }

    float bv[4];
    #pragma unroll
    for (int nf = 0; nf < 4; ++nf)
        bv[nf] = bias[n0 + wn * 64 + nf * 16 + lr];
    #pragma unroll
    for (int mf = 0; mf < 2; ++mf)
        #pragma unroll
        for (int nf = 0; nf < 4; ++nf)
            #pragma unroll
            for (int r = 0; r < 4; ++r) {
                const int m = m0 + wm * 32 + mf * 16 + lk * 4 + r;
                const int n = n0 + wn * 64 + nf * 16 + lr;
                float x = acc0[mf][nf][r] + bv[nf];
                x = fmaxf(x, 0.f);
                const f16 h = (f16)x;
                Ch[(size_t)m * N + n] = __builtin_bit_cast(ushort_t, h);
            }
}

// ---------------------------------------------------------------------------
// 1-limb fp16 GEMM for v = relu(q2 @ Wu + bu): 128x128 tile, 512 threads
// (r17-measured ~15 µs).
// ---------------------------------------------------------------------------
__global__ __launch_bounds__(512)
void mfma_gemm1l(const ushort_t* __restrict__ Ah, const ushort_t* __restrict__ Bh,
                 const float* __restrict__ bias, ushort_t* __restrict__ Ch,
                 int K, int N, int nbx)
{
    __shared__ __align__(16) ushort_t Ash[128 * 64];   // 16KB
    __shared__ __align__(16) ushort_t Bsh[128 * 64];   // 16KB

    const int tid = threadIdx.x;
    const int w = tid >> 6, l = tid & 63;
    const int wm = w >> 1, wn = w & 1;          // 4m x 2n wave grid
    const int lr = l & 15, lk = l >> 4;
    const int cpx = gridDim.x >> 3;
    const int orig = (blockIdx.x & 7) * cpx + (blockIdx.x >> 3);
    const int m0 = (orig / nbx) * 128, n0 = (orig % nbx) * 128;

    f32x4 acc0[2][4] = {};

    for (int k0 = 0; k0 < K; k0 += 64) {
        #pragma unroll
        for (int it = 0; it < 2; ++it) {
            const int c = it * 512 + tid;       // 0..1023
            const int r = c >> 3, kp = c & 7;
            const int kl = kp ^ (r & 7);
            const size_t offA = (size_t)(m0 + r) * K + k0 + kl * 8;
            const size_t offB = (size_t)(n0 + r) * K + k0 + kl * 8;
            gld_lds16(Ah + offA, &Ash[(size_t)c * 8]);
            gld_lds16(Bh + offB, &Bsh[(size_t)c * 8]);
        }
        __syncthreads();

        #pragma unroll
        for (int ks = 0; ks < 2; ++ks) {
            f16x8 ah[2];
            #pragma unroll
            for (int mf = 0; mf < 2; ++mf) {
                const int row = wm * 32 + mf * 16 + lr;
                const int kb  = ks * 4 + lk;
                ah[mf] = *(const f16x8*)&Ash[row * 64 + ((kb ^ (row & 7)) << 3)];
            }
            #pragma unroll
            for (int nf = 0; nf < 4; ++nf) {
                const int row = wn * 64 + nf * 16 + lr;
                const int kb  = ks * 4 + lk;
                const f16x8 bh = *(const f16x8*)&Bsh[row * 64 + ((kb ^ (row & 7)) << 3)];
                #pragma unroll
                for (int mf = 0; mf < 2; ++mf)
                    acc0[mf][nf] = __builtin_amdgcn_mfma_f32_16x16x32_f16(
                        ah[mf], bh, acc0[mf][nf], 0, 0, 0);
            }
        }
        __syncthreads();
    }

    float bv[4];
    #pragma unroll
    for (int nf = 0; nf < 4; ++nf)
        bv[nf] = bias[n0 + wn * 64 + nf * 16 + lr];
    #pragma unroll
    for (int mf = 0; mf < 2; ++mf)
        #pragma unroll
        for (int nf = 0; nf < 4; ++nf)
            #pragma unroll
            for (int r = 0; r < 4; ++r) {
                const int m = m0 + wm * 32 + mf * 16 + lk * 4 + r;
                const int n = n0 + wn * 64 + nf * 16 + lr;
                float x = acc0[mf][nf][r] + bv[nf];
                x = fmaxf(x, 0.f);
                const f16 hcv = (f16)x;
                Ch[(size_t)m * N + n] = __builtin_bit_cast(ushort_t, hcv);
            }
}

// ---------------------------------------------------------------------------
__global__ __launch_bounds__(256)
void tsplit2_kernel(const float* __restrict__ in, ushort_t* __restrict__ t0,
                    ushort_t* __restrict__ t1, int K, int N)
{
    __shared__ float tile[32][33];
    const int t = threadIdx.x;
    const int bk = blockIdx.x * 32, bn = blockIdx.y * 32;
    const int c = t & 31, rb = t >> 5;
    #pragma unroll
    for (int i = 0; i < 4; ++i) {
        const int r = rb + i * 8;
        tile[r][c] = in[(size_t)(bk + r) * N + bn + c];
    }
    __syncthreads();
    #pragma unroll
    for (int i = 0; i < 4; ++i) {
        const int rr = rb + i * 8;
        const float x = tile[c][rr];
        const f16 hv = (f16)x;
        const f16 lv = (f16)((x - (float)hv) * 2048.0f);
        const size_t o = (size_t)(bn + rr) * K + bk + c;
        t0[o] = __builtin_bit_cast(ushort_t, hv);
        t1[o] = __builtin_bit_cast(ushort_t, lv);
    }
}

// ---------------------------------------------------------------------------
__global__ __launch_bounds__(256)
void gemm_trans_kernel(const float* __restrict__ A, const float* __restrict__ Bm,
                       float* __restrict__ C, int M, int KA, int N)
{
    constexpr int BK = 16;
    __shared__ float Asb[BK][64 + 4];
    __shared__ float Bsb[BK][64 + 4];
    const int tid = threadIdx.x;
    const int tx = tid & 15, ty = tid >> 4;
    const int m0 = blockIdx.y * 64, n0 = blockIdx.x * 64;

    float acc[4][4] = {};
    const int lr = tid >> 2, lc = (tid & 3) << 2;
    const int kr = tid >> 4, nc = (tid & 15) << 2;

    for (int k0 = 0; k0 < KA; k0 += BK) {
        const float4 a4 = *reinterpret_cast<const float4*>(A + (size_t)(m0 + lr) * KA + k0 + lc);
        const float4 b4 = *reinterpret_cast<const float4*>(Bm + (size_t)(k0 + kr) * N + n0 + nc);
        Asb[lc + 0][lr] = a4.x; Asb[lc + 1][lr] = a4.y;
        Asb[lc + 2][lr] = a4.z; Asb[lc + 3][lr] = a4.w;
        *reinterpret_cast<float4*>(&Bsb[kr][nc]) = b4;
        __syncthreads();
        #pragma unroll
        for (int kk = 0; kk < BK; ++kk) {
            const float4 av = *reinterpret_cast<const float4*>(&Asb[kk][ty << 2]);
            const float4 bv = *reinterpret_cast<const float4*>(&Bsb[kk][tx << 2]);
            const float a[4] = {av.x, av.y, av.z, av.w};
            const float b[4] = {bv.x, bv.y, bv.z, bv.w};
            #pragma unroll
            for (int i = 0; i < 4; ++i)
                #pragma unroll
                for (int j = 0; j < 4; ++j)
                    acc[i][j] = fmaf(a[i], b[j], acc[i][j]);
        }
        __syncthreads();
    }
    #pragma unroll
    for (int i = 0; i < 4; ++i) {
        const int m = m0 + (ty << 2) + i;
        const int b = m >> 12, s = m & (S_ - 1);
        #pragma unroll
        for (int j = 0; j < 4; ++j) {
            const int n = n0 + (tx << 2) + j;
            C[(size_t)(b * N + n) * S_ + s] = acc[i][j];
        }
    }
}

// ---------------------------------------------------------------------------
__global__ __launch_bounds__(256)
void var_kernel(const float* __restrict__ rmvT, float* __restrict__ hvars)
{
    const int bk = blockIdx.x;
    const float* src = rmvT + (size_t)bk * S_;
    float s1 = 0.f, s2 = 0.f;
    for (int t = threadIdx.x; t < S_; t += 256) {
        const float v = src[t];
        s1 += v; s2 += v * v;
    }
    #pragma unroll
    for (int off = 32; off; off >>= 1) {
        s1 += __shfl_xor(s1, off);
        s2 += __shfl_xor(s2, off);
    }
    __shared__ float r1[4], r2[4];
    const int wave = threadIdx.x >> 6, lane = threadIdx.x & 63;
    if (lane == 0) { r1[wave] = s1; r2[wave] = s2; }
    __syncthreads();
    if (threadIdx.x == 0) {
        const float t1 = r1[0] + r1[1] + r1[2] + r1[3];
        const float t2 = r2[0] + r2[1] + r2[2] + r2[3];
        const float mu = t1 / (float)S_;
        hvars[bk] = t2 / (float)S_ - mu * mu;
    }
}

__global__ void topk_kernel(const float* __restrict__ hvars, int* __restrict__ topidx)
{
    const int b = threadIdx.x;
    if (b >= B_) return;
    float v[KK];
    for (int k = 0; k < KK; ++k) v[k] = hvars[b * KK + k];
    for (int i = 0; i < KH; ++i) {
        int best = 0; float bv = -3.4e38f;
        for (int k = 0; k < KK; ++k)
            if (v[k] > bv) { bv = v[k]; best = k; }
        topidx[b * KH + i] = best;
        v[best] = -3.4e38f;
    }
}

// ---------------------------------------------------------------------------
__global__ __launch_bounds__(256)
void rank_kernel(const float* __restrict__ rmvT, const int* __restrict__ topidx,
                 int* __restrict__ gidx)
{
    const int bi = blockIdx.x;
    const int b = bi >> 2, ih = bi & 3;
    const int k = topidx[b * KH + ih];
    const float* src = rmvT + (size_t)(b * KK + k) * S_;
    __shared__ __align__(16) unsigned long long keys[S_];
    __shared__ int partial[4][64];
    for (int t = threadIdx.x; t < S_; t += 256) {
        const unsigned bits = __builtin_bit_cast(unsigned, src[t]);
        const unsigned u = (bits & 0x80000000u) ? ~bits : (bits | 0x80000000u);
        keys[t] = ((unsigned long long)u << 12) | (unsigned)t;
    }
    __syncthreads();

    const int il = threadIdx.x & 63;
    const int chunk = threadIdx.x >> 6;
    const int i = blockIdx.y * 64 + il;
    const unsigned long long ki = keys[i];

    int cnt = 0;
    const int jbase = chunk << 10;
    #pragma unroll 8
    for (int jj = 0; jj < 1024; jj += 2) {
        const ulonglong2 k2 = *reinterpret_cast<const ulonglong2*>(&keys[jbase + jj]);
        cnt += (int)(k2.x < ki);
        cnt += (int)(k2.y < ki);
    }
    partial[chunk][il] = cnt;
    __syncthreads();
    if (threadIdx.x < 64) {
        const int rank = partial[0][threadIdx.x] + partial[1][threadIdx.x]
                       + partial[2][threadIdx.x] + partial[3][threadIdx.x];
        const int ii = blockIdx.y * 64 + threadIdx.x;
        gidx[((b << 12) + rank) * KH + ih] = (b << 12) + ii;
    }
}

// ---------------------------------------------------------------------------
// Barrier-free fused scores + window sum + residual + LayerNorm (f16 q2h).
// ---------------------------------------------------------------------------
__global__ __launch_bounds__(256)
void final_kernel(const ushort_t* __restrict__ vh, const ushort_t* __restrict__ q2h,
                  const float* __restrict__ inputs, const float* __restrict__ gamma,
                  const float* __restrict__ beta, float* __restrict__ out)
{
    const int bid = blockIdx.x;                            // 4096 blocks
    const int m0 = (((bid & 7) << 9) | (bid >> 3)) << 2;   // XCD swizzle, 4 rows
    const int wave = threadIdx.x >> 6, lane = threadIdx.x & 63;
    const int m = m0 + wave;
    const int s = m & (S_ - 1), b = m >> 12;
    const int jb = (s < 4) ? 0 : (s >= S_ - 4 ? S_ - WW : s - 4);

    const ushort_t* vb = vh + (size_t)(b * S_ + jb) * DH;
    const float* inp = inputs + (size_t)m * DH;
    f16x8 varr[2][WW];
    float4 iv[2][2];
    #pragma unroll
    for (int c = 0; c < 2; ++c) {
        const int h = (c << 9) + (lane << 3);
        #pragma unroll
        for (int w = 0; w < WW; ++w)
            varr[c][w] = *reinterpret_cast<const f16x8*>(vb + (size_t)w * DH + h);
        iv[c][0] = *reinterpret_cast<const float4*>(inp + h);
        iv[c][1] = *reinterpret_cast<const float4*>(inp + h + 4);
    }

    const ushort4 qv4 = *reinterpret_cast<const ushort4*>(q2h + (size_t)m * DL + (lane << 2));
    const float qx = (float)__builtin_bit_cast(f16, qv4.x);
    const float qy = (float)__builtin_bit_cast(f16, qv4.y);
    const float qz = (float)__builtin_bit_cast(f16, qv4.z);
    const float qw = (float)__builtin_bit_cast(f16, qv4.w);
    const ushort_t* kbase = q2h + (size_t)(b * S_ + jb) * DL;
    float sc[WW];
    #pragma unroll
    for (int w = 0; w < WW; ++w) {
        const ushort4 kv4 = *reinterpret_cast<const ushort4*>(kbase + w * DL + (lane << 2));
        float d = qx * (float)__builtin_bit_cast(f16, kv4.x)
                + qy * (float)__builtin_bit_cast(f16, kv4.y)
                + qz * (float)__builtin_bit_cast(f16, kv4.z)
                + qw * (float)__builtin_bit_cast(f16, kv4.w);
        #pragma unroll
        for (int off = 32; off; off >>= 1) d += __shfl_xor(d, off);
        sc[w] = d * 0.0625f;
    }
    float mx = sc[0];
    #pragma unroll
    for (int w = 1; w < WW; ++w) mx = fmaxf(mx, sc[w]);
    float wgt[WW]; float sum = 0.f;
    #pragma unroll
    for (int w = 0; w < WW; ++w) { wgt[w] = __expf(sc[w] - mx); sum += wgt[w]; }
    const float inv = 1.f / sum;
    #pragma unroll
    for (int w = 0; w < WW; ++w) wgt[w] *= inv;

    float x[2][8];
    float s1 = 0.f, s2 = 0.f;
    #pragma unroll
    for (int c = 0; c < 2; ++c) {
        float acc[8] = {};
        #pragma unroll
        for (int w = 0; w < WW; ++w) {
            const f16x8 vv = varr[c][w];
            #pragma unroll
            for (int e = 0; e < 8; ++e)
                acc[e] = fmaf(wgt[w], (float)vv[e], acc[e]);
        }
        #pragma unroll
        for (int e = 0; e < 8; ++e) {
            const float ivv = (e < 4) ? (&iv[c][0].x)[e] : (&iv[c][1].x)[e - 4];
            acc[e] += ivv;
            x[c][e] = acc[e];
            s1 += acc[e];
            s2 += acc[e] * acc[e];
        }
    }

    #pragma unroll
    for (int off = 32; off; off >>= 1) {
        s1 += __shfl_xor(s1, off);
        s2 += __shfl_xor(s2, off);
    }
    const float mu = s1 / (float)DH;
    const float rs = rsqrtf(s2 / (float)DH - mu * mu + 0.001f);

    #pragma unroll
    for (int c = 0; c < 2; ++c) {
        const int h = (c << 9) + (lane << 3);
        #pragma unroll
        for (int half = 0; half < 2; ++half) {
            const float4 g  = *reinterpret_cast<const float4*>(gamma + h + half * 4);
            const float4 bt = *reinterpret_cast<const float4*>(beta + h + half * 4);
            float4 o;
            o.x = g.x * (x[c][half * 4 + 0] - mu) * rs + bt.x;
            o.y = g.y * (x[c][half * 4 + 1] - mu) * rs + bt.y;
            o.z = g.z * (x[c][half * 4 + 2] - mu) * rs + bt.z;
            o.w = g.w * (x[c][half * 4 + 3] - mu) * rs + bt.w;
            *reinterpret_cast<float4*>(out + (size_t)m * DH + h + half * 4) = o;
        }
    }
}

// ---------------------------------------------------------------------------
extern "C" void kernel_launch(void* const* d_in, const int* in_sizes, int n_in,
                              void* d_out, int out_size, void* d_ws, size_t ws_size,
                              hipStream_t stream)
{
    (void)in_sizes; (void)n_in; (void)out_size; (void)ws_size;
    const float* inputs = (const float*)d_in[0];
    const float* W1     = (const float*)d_in[1];
    const float* b1     = (const float*)d_in[2];
    const float* RME    = (const float*)d_in[3];
    const float* K2     = (const float*)d_in[4];
    const float* b2     = (const float*)d_in[5];
    const float* Wu     = (const float*)d_in[6];
    const float* bu     = (const float*)d_in[7];
    const float* gamma  = (const float*)d_in[8];
    const float* beta   = (const float*)d_in[9];
    float* out = (float*)d_out;

    char* ws = (char*)d_ws;
    const size_t MB = 1u << 20;
    ushort_t* vh  = (ushort_t*)(ws + 0 * MB);      // 32MB f16 v
    float*    q   = (float*)   (ws + 64 * MB);     // 16MB
    ushort_t* qh  = (ushort_t*)(ws + 80 * MB);     // 8MB
    ushort_t* q2h = (ushort_t*)(ws + 112 * MB);    // 8MB
    float*    rmvT= (float*)   (ws + 128 * MB);    // 4MB
    float*    hvars  = (float*)(ws + 132 * MB);
    int*      topidx = (int*)  (ws + 132 * MB + 4096);
    int*      gidx   = (int*)  (ws + 132 * MB + 8192);   // 256KB
    ushort_t* w1th = (ushort_t*)(ws + 133 * MB);
    ushort_t* w1tl = w1th + (DH * DL);
    ushort_t* k2th = w1tl + (DH * DL);
    ushort_t* k2tl = k2th + (KH * DL * DL);
    ushort_t* wuth = k2tl + (KH * DL * DL);
    ushort_t* wutl = wuth + (DL * DH);

    const int M = B_ * S_;

    // 0. transpose+split weights (tiny)
    tsplit2_kernel<<<dim3(DH / 32, DL / 32), dim3(256), 0, stream>>>(W1, w1th, w1tl, DH, DL);
    tsplit2_kernel<<<dim3(KH * DL / 32, DL / 32), dim3(256), 0, stream>>>((const float*)K2, k2th, k2tl, KH * DL, DL);
    tsplit2_kernel<<<dim3(DL / 32, DH / 32), dim3(256), 0, stream>>>(Wu, wuth, wutl, DL, DH);

    // 1. q = relu(inputs @ W1 + b1) — 2-limb 64x128, fp32 q + f16 qh
    mfma_gemm2<<<dim3((DL / 128) * (M / 64)), dim3(256), 0, stream>>>(
        inputs, w1th, w1tl, b1, q, qh, DH, DL, DL / 128);
    // 2. RMVsT[b][k][s] = (q @ RME)^T  (fp32, key path)
    gemm_trans_kernel<<<dim3(KK / 64, M / 64), dim3(256), 0, stream>>>(q, RME, rmvT, M, DL, KK);
    // 3-5. variance, top-4 heads, u64 rank argsort -> gather table
    var_kernel<<<dim3(B_ * KK), dim3(256), 0, stream>>>(rmvT, hvars);
    topk_kernel<<<dim3(1), dim3(64), 0, stream>>>(hvars, topidx);
    rank_kernel<<<dim3(B_ * KH, S_ / 64), dim3(256), 0, stream>>>(rmvT, topidx, gidx);
    // 6. q2h = f16(relu(gather(qh) @ K2h + b2)) — 1-limb gather 64x128
    gemm6_1l<<<dim3((DL / 128) * (M / 64)), dim3(256), 0, stream>>>(
        qh, k2th, b2, q2h, gidx, KH * DL, DL, DL / 128);
    // 7. v = relu(q2 @ Wu + bu) — 1-limb 128x128, f16 out
    mfma_gemm1l<<<dim3((DH / 128) * (M / 128)), dim3(512), 0, stream>>>(
        q2h, wuth, bu, vh, DL, DH, DH / 128);
    // 8+9. barrier-free fused scores + window sum + residual + LayerNorm
    final_kernel<<<dim3(M / 4), dim3(256), 0, stream>>>(vh, q2h, inputs, gamma, beta, out);
}